// Round 1
// baseline (406.321 us; speedup 1.0000x reference)
//
#include <hip/hip_runtime.h>
#include <cstdint>
#include <cstddef>

#define N_NODES 100000
#define N_EDGES 1600000

// ---------------- utility kernels ----------------

__global__ void k_zero2(int* __restrict__ cnt, int* __restrict__ cur, int n) {
    int i = blockIdx.x * 256 + threadIdx.x;
    if (i < n) { cnt[i] = 0; cur[i] = 0; }
}

__global__ void k_count(const int* __restrict__ dst, int* __restrict__ cnt, int E) {
    int e = blockIdx.x * 256 + threadIdx.x;
    if (e < E) atomicAdd(&cnt[dst[e]], 1);
}

__global__ void k_dinv(const int* __restrict__ cnt, float* __restrict__ dinv, int n) {
    int i = blockIdx.x * 256 + threadIdx.x;
    if (i < n) dinv[i] = rsqrtf((float)cnt[i] + 1.0f);  // +1 self-loop; deg>=1 always
}

// ---------------- scan (exclusive prefix over cnt -> off) ----------------

__global__ void k_scan_blk(const int* __restrict__ cnt, int* __restrict__ off,
                           int* __restrict__ blksum, int n) {
    __shared__ int s[256];
    int t = threadIdx.x;
    int i = blockIdx.x * 256 + t;
    int v = (i < n) ? cnt[i] : 0;
    s[t] = v;
    __syncthreads();
    for (int o = 1; o < 256; o <<= 1) {
        int add = (t >= o) ? s[t - o] : 0;
        __syncthreads();
        s[t] += add;
        __syncthreads();
    }
    if (i < n) off[i] = s[t] - v;            // exclusive within block
    if (t == 255) blksum[blockIdx.x] = s[255];
}

__global__ void k_scan_top(int* __restrict__ blksum, int nb) {
    __shared__ int s[512];
    int t = threadIdx.x;
    int v = (t < nb) ? blksum[t] : 0;
    s[t] = v;
    __syncthreads();
    for (int o = 1; o < 512; o <<= 1) {
        int add = (t >= o) ? s[t - o] : 0;
        __syncthreads();
        s[t] += add;
        __syncthreads();
    }
    if (t < nb) blksum[t] = s[t] - v;        // exclusive
}

__global__ void k_scan_add(int* __restrict__ off, const int* __restrict__ blksum, int n) {
    int i = blockIdx.x * 256 + threadIdx.x;
    if (i < n) off[i] += blksum[blockIdx.x];
}

__global__ void k_place(const int* __restrict__ src, const int* __restrict__ dst,
                        const int* __restrict__ off, int* __restrict__ cur,
                        int* __restrict__ es, int E) {
    int e = blockIdx.x * 256 + threadIdx.x;
    if (e < E) {
        int d = dst[e];
        int p = off[d] + atomicAdd(&cur[d], 1);
        es[p] = src[e];
    }
}

// ---------------- GEMM1: hw1 = x[M,256] @ w1[256,64] ----------------

__global__ __launch_bounds__(256) void k_gemm1(const float* __restrict__ x,
                                               const float* __restrict__ w,
                                               float* __restrict__ out, int M) {
    __shared__ float xs[64][64];   // [row][k]
    __shared__ float ws[64][64];   // [k][c]
    int t = threadIdx.x;
    int row0 = blockIdx.x * 64;
    int tx = t & 15;               // col quad -> cols tx*4..+3
    int ty = t >> 4;               // row group -> rows ty*4..+3
    float acc[4][4] = {};

    for (int kb = 0; kb < 256; kb += 64) {
        __syncthreads();
        {
            int q = t & 15;        // quad within row
            int r = t >> 4;        // 16 rows per pass
#pragma unroll
            for (int p = 0; p < 4; p++) {
                int rr = r + p * 16;
                int grow = row0 + rr; if (grow >= M) grow = M - 1;
                float4 v = *(const float4*)&x[(size_t)grow * 256 + kb + q * 4];
                *(float4*)&xs[rr][q * 4] = v;
            }
#pragma unroll
            for (int p = 0; p < 4; p++) {
                int rr = r + p * 16;
                float4 v = *(const float4*)&w[(size_t)(kb + rr) * 64 + q * 4];
                *(float4*)&ws[rr][q * 4] = v;
            }
        }
        __syncthreads();
#pragma unroll 8
        for (int k = 0; k < 64; k++) {
            float4 b = *(const float4*)&ws[k][tx * 4];
#pragma unroll
            for (int i = 0; i < 4; i++) {
                float a = xs[ty * 4 + i][k];
                acc[i][0] += a * b.x;
                acc[i][1] += a * b.y;
                acc[i][2] += a * b.z;
                acc[i][3] += a * b.w;
            }
        }
    }
#pragma unroll
    for (int i = 0; i < 4; i++) {
        int grow = row0 + ty * 4 + i;
        if (grow < M) {
            float4 v;
            v.x = acc[i][0]; v.y = acc[i][1]; v.z = acc[i][2]; v.w = acc[i][3];
            *(float4*)&out[(size_t)grow * 64 + tx * 4] = v;
        }
    }
}

// ---------------- GEMM2: hw2 = h1[M,64] @ w2[64,32] ----------------

__global__ __launch_bounds__(256) void k_gemm2(const float* __restrict__ h,
                                               const float* __restrict__ w,
                                               float* __restrict__ out, int M) {
    __shared__ float hs[64][64];
    __shared__ float ws2[64][32];
    int t = threadIdx.x;
    int row0 = blockIdx.x * 64;
    {
        int q = t & 15, r = t >> 4;
#pragma unroll
        for (int p = 0; p < 4; p++) {
            int rr = r + p * 16;
            int grow = row0 + rr; if (grow >= M) grow = M - 1;
            *(float4*)&hs[rr][q * 4] = *(const float4*)&h[(size_t)grow * 64 + q * 4];
        }
#pragma unroll
        for (int p = 0; p < 2; p++) {
            int idx = t + p * 256;           // 512 float4s total
            int kr = idx >> 3, cq = idx & 7;
            *(float4*)&ws2[kr][cq * 4] = *(const float4*)&w[(size_t)kr * 32 + cq * 4];
        }
    }
    __syncthreads();
    int tx = t & 7;                 // cols tx*4..+3
    int ty = t >> 3;                // rows ty*2..+1
    float acc[2][4] = {};
#pragma unroll 8
    for (int k = 0; k < 64; k++) {
        float4 b = *(const float4*)&ws2[k][tx * 4];
        float a0 = hs[ty * 2 + 0][k];
        float a1 = hs[ty * 2 + 1][k];
        acc[0][0] += a0 * b.x; acc[0][1] += a0 * b.y; acc[0][2] += a0 * b.z; acc[0][3] += a0 * b.w;
        acc[1][0] += a1 * b.x; acc[1][1] += a1 * b.y; acc[1][2] += a1 * b.z; acc[1][3] += a1 * b.w;
    }
#pragma unroll
    for (int i = 0; i < 2; i++) {
        int grow = row0 + ty * 2 + i;
        if (grow < M) {
            float4 v;
            v.x = acc[i][0]; v.y = acc[i][1]; v.z = acc[i][2]; v.w = acc[i][3];
            *(float4*)&out[(size_t)grow * 32 + tx * 4] = v;
        }
    }
}

// ---------------- aggregation: h_out[n][D] = relu( A_hat @ hw + bias ) ----------------
// lane c of the node's thread-group holds feature c; CSR edge list es[off..off+cnt)

template <int D>
__global__ __launch_bounds__(256) void k_agg(const float* __restrict__ hw,
                                             const float* __restrict__ dinv,
                                             const int* __restrict__ cnt,
                                             const int* __restrict__ off,
                                             const int* __restrict__ es,
                                             const float* __restrict__ bias,
                                             float* __restrict__ hout, int n) {
    int t = blockIdx.x * 256 + threadIdx.x;
    int node = t / D;
    int c = t % D;
    if (node >= n) return;
    float dn = dinv[node];
    float acc = dn * dn * hw[(size_t)node * D + c];   // self-loop term
    int base = off[node];
    int m = cnt[node];
    int j = 0;
    for (; j + 1 < m; j += 2) {
        int s0 = es[base + j];
        int s1 = es[base + j + 1];
        float w0 = dn * dinv[s0];
        float w1 = dn * dinv[s1];
        float v0 = hw[(size_t)s0 * D + c];
        float v1 = hw[(size_t)s1 * D + c];
        acc += w0 * v0;
        acc += w1 * v1;
    }
    if (j < m) {
        int s0 = es[base + j];
        acc += dn * dinv[s0] * hw[(size_t)s0 * D + c];
    }
    acc += bias[c];
    hout[(size_t)node * D + c] = fmaxf(acc, 0.0f);
}

// ---------------- final MLP head: out = relu(h2@wf1+bf1) @ wf2 + bf2 ----------------

__global__ __launch_bounds__(256) void k_final(const float* __restrict__ h2,
                                               const float* __restrict__ wf1,
                                               const float* __restrict__ bf1,
                                               const float* __restrict__ wf2,
                                               const float* __restrict__ bf2,
                                               float* __restrict__ out, int n) {
    __shared__ float W1[512];   // 32x16
    __shared__ float B1[16];
    __shared__ float W2[16];
    __shared__ float B2;
    int t = threadIdx.x;
    if (t < 256) { W1[t] = wf1[t]; W1[t + 256] = wf1[t + 256]; }
    if (t < 16) { B1[t] = bf1[t]; W2[t] = wf2[t]; }
    if (t == 0) B2 = bf2[0];
    __syncthreads();
    int i = blockIdx.x * 256 + t;
    if (i >= n) return;
    float h[32];
    const float4* hp = (const float4*)&h2[(size_t)i * 32];
#pragma unroll
    for (int q = 0; q < 8; q++) {
        float4 v = hp[q];
        h[q * 4 + 0] = v.x; h[q * 4 + 1] = v.y; h[q * 4 + 2] = v.z; h[q * 4 + 3] = v.w;
    }
    float o = B2;
#pragma unroll
    for (int jj = 0; jj < 16; jj++) {
        float s = B1[jj];
#pragma unroll
        for (int k = 0; k < 32; k++) s += h[k] * W1[k * 16 + jj];
        o += fmaxf(s, 0.0f) * W2[jj];
    }
    out[i] = o;
}

// ---------------- host ----------------

extern "C" void kernel_launch(void* const* d_in, const int* in_sizes, int n_in,
                              void* d_out, int out_size, void* d_ws, size_t ws_size,
                              hipStream_t stream) {
    const float* x   = (const float*)d_in[0];
    const int*   ei  = (const int*)d_in[1];
    const float* w1  = (const float*)d_in[2];
    const float* b1  = (const float*)d_in[3];
    const float* w2  = (const float*)d_in[4];
    const float* b2  = (const float*)d_in[5];
    const float* wf1 = (const float*)d_in[6];
    const float* bf1 = (const float*)d_in[7];
    const float* wf2 = (const float*)d_in[8];
    const float* bf2 = (const float*)d_in[9];

    const int n = N_NODES;
    const int E = N_EDGES;
    const int* srcp = ei;        // edge_index[0]
    const int* dstp = ei + E;    // edge_index[1]

    char* p = (char*)d_ws;
    auto take = [&](size_t bytes) {
        char* r = p;
        p += (bytes + 255) & ~(size_t)255;
        return r;
    };
    float* dinv  = (float*)take((size_t)n * 4);
    int*   cnt   = (int*)take((size_t)n * 4);
    int*   off   = (int*)take((size_t)n * 4);
    int*   cur   = (int*)take((size_t)n * 4);
    int*   blksum= (int*)take(4096);
    int*   es    = (int*)take((size_t)E * 4);
    float* hw1   = (float*)take((size_t)n * 64 * 4);
    float* h1    = (float*)take((size_t)n * 64 * 4);
    float* hw2 = hw1;   // reuse after layer-1 aggregation consumed hw1
    float* h2  = h1;    // reuse after gemm2 consumed h1

    int gn = (n + 255) / 256;
    int gE = (E + 255) / 256;
    int NB = (n + 255) / 256;   // 391 blocks of scan

    k_zero2<<<gn, 256, 0, stream>>>(cnt, cur, n);
    k_count<<<gE, 256, 0, stream>>>(dstp, cnt, E);
    k_dinv<<<gn, 256, 0, stream>>>(cnt, dinv, n);
    k_scan_blk<<<NB, 256, 0, stream>>>(cnt, off, blksum, n);
    k_scan_top<<<1, 512, 0, stream>>>(blksum, NB);
    k_scan_add<<<NB, 256, 0, stream>>>(off, blksum, n);
    k_place<<<gE, 256, 0, stream>>>(srcp, dstp, off, cur, es, E);

    k_gemm1<<<(n + 63) / 64, 256, 0, stream>>>(x, w1, hw1, n);
    k_agg<64><<<((size_t)n * 64 + 255) / 256, 256, 0, stream>>>(hw1, dinv, cnt, off, es, b1, h1, n);
    k_gemm2<<<(n + 63) / 64, 256, 0, stream>>>(h1, w2, hw2, n);
    k_agg<32><<<((size_t)n * 32 + 255) / 256, 256, 0, stream>>>(hw2, dinv, cnt, off, es, b2, h2, n);
    k_final<<<gn, 256, 0, stream>>>(h2, wf1, bf1, wf2, bf2, (float*)d_out, n);
}